// Round 1
// baseline (82.929 us; speedup 1.0000x reference)
//
#include <hip/hip_runtime.h>

#define T        64     // num_thetas
#define S        32     // bump_steps
#define NGRAPH   64
#define CHUNK    64     // nodes per block
#define SPT      8      // s-values per thread (256 threads = 4 waves x 64 lanes)

// Each block: 64 contiguous nodes. lane = theta t, wave = s-group (8 s each).
// sigmoid(100*(lin_s - nh)) = 1/(1 + exp2((nh - lin_s)*100*log2(e)))
// lin uniformly spaced => e_s geometric: ONE exp2 per (node,thread), 8 rcp.
__global__ __launch_bounds__(256) void ect_kernel(
    const float* __restrict__ x, const float* __restrict__ v,
    const float* __restrict__ lin, const int* __restrict__ batch,
    float* __restrict__ out, int n_points)
{
    __shared__ float sx[CHUNK * 3];
    __shared__ int   sb[CHUNK];

    const int tid = threadIdx.x;
    const int t   = tid & 63;
    const int s0  = (tid >> 6) * SPT;

    const float K = 144.26950408889634f;  // 100 * log2(e)

    const float v0 = v[0 * T + t];
    const float v1 = v[1 * T + t];
    const float v2 = v[2 * T + t];

    const float c0 = lin[s0] * K;                         // this thread's first threshold
    const float m  = __builtin_amdgcn_exp2f((lin[0] - lin[1]) * K); // geometric step 2^{-spacing*K}

    float acc[SPT];
#pragma unroll
    for (int j = 0; j < SPT; j++) acc[j] = 0.0f;

    const int base = blockIdx.x * CHUNK;
    const int rem  = min(CHUNK, n_points - base);

    if (tid < rem * 3) sx[tid] = x[base * 3 + tid];
    if (tid < rem)     sb[tid] = batch[base + tid];
    __syncthreads();

    int cur = sb[0];
    for (int n = 0; n < rem; n++) {
        const int b = sb[n];            // block-uniform
        if (b != cur) {                 // rare: graph boundary inside chunk
            float* o = out + (cur * S + s0) * T + t;
#pragma unroll
            for (int j = 0; j < SPT; j++) {
                atomicAdd(o + j * T, acc[j]);
                acc[j] = 0.0f;
            }
            cur = b;
        }
        const float x0 = sx[n * 3 + 0];
        const float x1 = sx[n * 3 + 1];
        const float x2 = sx[n * 3 + 2];
        const float nh = x0 * v0 + x1 * v1 + x2 * v2;
        float e = __builtin_amdgcn_exp2f(nh * K - c0);   // e_{s0}; inf/0 saturate correctly
#pragma unroll
        for (int j = 0; j < SPT; j++) {
            acc[j] += __builtin_amdgcn_rcpf(1.0f + e);   // sigmoid
            e *= m;                                      // next s: geometric step
        }
    }
    // final flush
    float* o = out + (cur * S + s0) * T + t;
#pragma unroll
    for (int j = 0; j < SPT; j++) atomicAdd(o + j * T, acc[j]);
}

extern "C" void kernel_launch(void* const* d_in, const int* in_sizes, int n_in,
                              void* d_out, int out_size, void* d_ws, size_t ws_size,
                              hipStream_t stream) {
    const float* x     = (const float*)d_in[0];   // [N,3]
    const float* v     = (const float*)d_in[1];   // [3,64]
    const float* lin   = (const float*)d_in[2];   // [32]
    const int*   batch = (const int*)d_in[3];     // [N], sorted
    float* out = (float*)d_out;                   // [64,32,64]

    const int n_points = in_sizes[0] / 3;
    const int blocks   = (n_points + CHUNK - 1) / CHUNK;

    // harness poisons d_out with 0xAA before every timed replay
    hipMemsetAsync(d_out, 0, (size_t)out_size * sizeof(float), stream);
    ect_kernel<<<blocks, 256, 0, stream>>>(x, v, lin, batch, out, n_points);
}